// Round 13
// baseline (251.923 us; speedup 1.0000x reference)
//
#include <hip/hip_runtime.h>
#include <math.h>

#define D 2048
#define E 64
#define TOK 64                 // tokens per block tile

typedef float4 f4;

__device__ __forceinline__ float fget(const float4 v, int j) {
    return j == 0 ? v.x : j == 1 ? v.y : j == 2 ? v.z : v.w;
}

// 64 FMAs: outer product acc[8][8] += x8 (x) w8. All operands in VGPRs.
__device__ __forceinline__ void fmablock(float (&acc)[8][8],
                                         const float4 (&xw)[2],
                                         const float4 (&ww)[2]) {
#pragma unroll
    for (int t = 0; t < 8; ++t) {
        const float xt = fget(t < 4 ? xw[0] : xw[1], t & 3);
#pragma unroll
        for (int e = 0; e < 8; ++e) {
            const float we = fget(e < 4 ? ww[0] : ww[1], e & 3);
            acc[t][e] = fmaf(xt, we, acc[t][e]);
        }
    }
}

// Tree-tile IO on [64 tok][64 exp] fp32 (epilogue-only).
__device__ __forceinline__ void tile_store(float* b, const float (&acc)[8][8],
                                           int tg, int eg) {
#pragma unroll
    for (int t = 0; t < 8; ++t) {
        f4 v0 = {acc[t][0], acc[t][1], acc[t][2], acc[t][3]};
        f4 v1 = {acc[t][4], acc[t][5], acc[t][6], acc[t][7]};
        *(f4*)(b + (tg * 8 + t) * 64 + eg * 8) = v0;
        *(f4*)(b + (tg * 8 + t) * 64 + eg * 8 + 4) = v1;
    }
}

__device__ __forceinline__ void tile_addin(const float* b, float (&acc)[8][8],
                                           int tg, int eg) {
#pragma unroll
    for (int t = 0; t < 8; ++t) {
        f4 v0 = *(const f4*)(b + (tg * 8 + t) * 64 + eg * 8);
        f4 v1 = *(const f4*)(b + (tg * 8 + t) * 64 + eg * 8 + 4);
        acc[t][0] += v0.x; acc[t][1] += v0.y; acc[t][2] += v0.z; acc[t][3] += v0.w;
        acc[t][4] += v1.x; acc[t][5] += v1.y; acc[t][6] += v1.z; acc[t][7] += v1.w;
    }
}

// ---------------- kernel 1: K-eighth partial GEMM, 2-wave blocks ----------------
// Round-12 post-mortem: residency data across r7-r12 fits a ~64 KB CU LDS
// scheduling budget (32KB->2.65 blocks, 64KB->1, 128KB->1), block latency
// invariant ~27 us -> wall = 27 x grid/(256 x resident). Lever: LDS/block.
// This round: SINGLE-buffered SK=16 staging (8 KB/wave, 16 KB/block -> 4
// blocks resident). Same-wave DS ordering makes in-place overwrite safe:
// next-step row j may be written once current row j's prefetch (iter j-2)
// has issued. x-write row r at iter r; W written as 2 conflict-free b128
// pairs at iters 6 (rows 0-7, consumed by iter 5) and 14 (rows 8-15,
// consumed by iter 13); prefetch wraps (r+2)&15 into just-written rows at
// iters 14/15. x global regs double-set (full-step vmcnt cover); W single
// set reloaded at iter 15 (consumed next step iter 6).
#define NQ 8
#define KQ (D / NQ)            // 256 rows per block
#define KCH (KQ / 2)           // 128 rows per wave
#define SK 16                  // k-rows per staged step (64 B/lane x fetch)
#define NSTEP (KCH / SK)       // 8

template<bool STAGE, bool LOAD>
__device__ __forceinline__ void step_body(
    float (&acc)[8][8], float4 (&xw)[2][2], float4 (&ww)[2][2],
    float* xbuf, float* wbuf, int tg, int eg, int lane, int wso,
    float4 (&xsC)[4], float4 (&xsN)[4], float4 (&ws)[4],
    const float* xg, const float* wgl, int s2)
{
#pragma unroll
    for (int r = 0; r < 16; ++r) {
        const int p = r & 1;
        fmablock(acc, xw[p], ww[p]);
        if (STAGE) {
            // next-step x row r (current row r's LDS read issued at iter r-2,
            // or prev-step iters 14/15 for rows 0,1)
            xbuf[r * 64 + lane] = fget(xsC[r >> 2], r & 3);
            if (r == 6) {        // W rows 0..7 (current copies consumed @ iter 5)
                *(f4*)(wbuf + wso) = ws[0];
                *(f4*)(wbuf + wso + 32) = ws[1];
            }
            if (r == 14) {       // W rows 8..15 (current consumed @ iter 13)
                *(f4*)(wbuf + 512 + wso) = ws[2];
                *(f4*)(wbuf + 512 + wso + 32) = ws[3];
            }
        }
        if (LOAD) {
            if (r == 0) {        // step s+2 x -> NXT regs (one 64B line/lane)
#pragma unroll
                for (int c = 0; c < 4; ++c)
                    xsN[c] = *(const f4*)(xg + s2 * SK + c * 4);
            }
            if (r == 15) {       // step s+2 W (ws pairs written at 6/14 above)
                ws[0] = *(const f4*)(wgl + (size_t)s2 * SK * E);
                ws[1] = *(const f4*)(wgl + (size_t)s2 * SK * E + 32);
                ws[2] = *(const f4*)(wgl + (size_t)(s2 * SK + 8) * E);
                ws[3] = *(const f4*)(wgl + (size_t)(s2 * SK + 8) * E + 32);
            }
        }
        const int pr = (r + 2) & 15;     // iters 14/15 wrap into next-step rows
        xw[p][0] = *(const f4*)(xbuf + pr * 64 + tg * 8);
        xw[p][1] = *(const f4*)(xbuf + pr * 64 + tg * 8 + 4);
        ww[p][0] = *(const f4*)(wbuf + pr * 64 + eg * 8);
        ww[p][1] = *(const f4*)(wbuf + pr * 64 + eg * 8 + 4);
    }
}

__global__ __launch_bounds__(128)
void gating_mm(const float* __restrict__ x, const float* __restrict__ W,
               float* __restrict__ partial, int ntok)
{
    __shared__ __align__(16) float smem[4096];     // 16 KB

    const int tid  = threadIdx.x;
    const int lane = tid & 63;
    const int w    = __builtin_amdgcn_readfirstlane(tid >> 6);  // 0..1
    const int tg   = lane >> 3;          // token group (8 tokens)
    const int eg   = lane & 7;           // expert group (8 experts)
    const int q    = blockIdx.x & 7;     // K eighth
    const int tok0 = (blockIdx.x >> 3) * TOK;

    // per-wave private single-buffer staging: xT [16][64] + W [16][64]
    float* xbuf = smem + w * 2048;
    float* wbuf = xbuf + 1024;

    const float* xg  = x + (size_t)(tok0 + lane) * D + q * KQ + w * KCH;
    const float* wg  = W + (size_t)(q * KQ + w * KCH) * E;
    // W stage role: lane -> row (lane>>3), cols (lane&7)*4 and +32.
    // Global: 4 coalesced dwordx4 per 16 rows. LDS write: 8-lane groups are
    // 128B-contiguous -> conflict-free b128.
    const float* wgl = wg + (size_t)(lane >> 3) * E + (lane & 7) * 4;
    const int    wso = (lane >> 3) * 64 + (lane & 7) * 4;

    float acc[8][8];
#pragma unroll
    for (int t = 0; t < 8; ++t)
#pragma unroll
        for (int e = 0; e < 8; ++e) acc[t][e] = 0.f;

    float4 xsA[4], xsB[4], ws[4];
    // ---- prologue: stage step 0, load step 1, prime rows 0/1 ----
#pragma unroll
    for (int c = 0; c < 4; ++c) xsA[c] = *(const f4*)(xg + c * 4);
    ws[0] = *(const f4*)(wgl);
    ws[1] = *(const f4*)(wgl + 32);
    ws[2] = *(const f4*)(wgl + 8 * E);
    ws[3] = *(const f4*)(wgl + 8 * E + 32);
#pragma unroll
    for (int j = 0; j < 16; ++j) xbuf[j * 64 + lane] = fget(xsA[j >> 2], j & 3);
    *(f4*)(wbuf + wso) = ws[0];
    *(f4*)(wbuf + wso + 32) = ws[1];
    *(f4*)(wbuf + 512 + wso) = ws[2];
    *(f4*)(wbuf + 512 + wso + 32) = ws[3];
    // step-1 loads (regs free after the staging writes consumed them)
#pragma unroll
    for (int c = 0; c < 4; ++c) xsA[c] = *(const f4*)(xg + SK + c * 4);
    ws[0] = *(const f4*)(wgl + (size_t)SK * E);
    ws[1] = *(const f4*)(wgl + (size_t)SK * E + 32);
    ws[2] = *(const f4*)(wgl + (size_t)(SK + 8) * E);
    ws[3] = *(const f4*)(wgl + (size_t)(SK + 8) * E + 32);

    float4 xw[2][2], ww[2][2];
    xw[0][0] = *(const f4*)(xbuf + tg * 8);
    xw[0][1] = *(const f4*)(xbuf + tg * 8 + 4);
    ww[0][0] = *(const f4*)(wbuf + eg * 8);
    ww[0][1] = *(const f4*)(wbuf + eg * 8 + 4);
    xw[1][0] = *(const f4*)(xbuf + 64 + tg * 8);
    xw[1][1] = *(const f4*)(xbuf + 64 + tg * 8 + 4);
    ww[1][0] = *(const f4*)(wbuf + 64 + eg * 8);
    ww[1][1] = *(const f4*)(wbuf + 64 + eg * 8 + 4);

    // ---- K loop: steps 0..7. CUR regs hold step s+1 data; NXT <- step s+2.
    // xs alternates A/B by step parity; ws single-set (reload iter 15).
#pragma unroll 1
    for (int ss = 0; ss < 3; ++ss) {
        step_body<true, true>(acc, xw, ww, xbuf, wbuf, tg, eg, lane, wso,
                              xsA, xsB, ws, xg, wgl, 2 * ss + 2);
        step_body<true, true>(acc, xw, ww, xbuf, wbuf, tg, eg, lane, wso,
                              xsB, xsA, ws, xg, wgl, 2 * ss + 3);
    }
    // step 6: stage step-7 tiles (CUR=A), no new loads
    step_body<true, false>(acc, xw, ww, xbuf, wbuf, tg, eg, lane, wso,
                           xsA, xsB, ws, xg, wgl, 0);
    // step 7: compute only
    step_body<false, false>(acc, xw, ww, xbuf, wbuf, tg, eg, lane, wso,
                            xsB, xsA, ws, xg, wgl, 0);

    // ---- cross-wave K-reduction: 2 -> 1 (single barrier pair) ----
    __syncthreads();                     // staging slices dead
    if (w == 1) tile_store(smem, acc, tg, eg);
    __syncthreads();
    if (w == 0) {
        tile_addin(smem, acc, tg, eg);   // full eighth sum
        float* pq = partial + ((size_t)q * ntok + tok0) * E;
#pragma unroll
        for (int t = 0; t < 8; ++t) {
            f4 v0 = {acc[t][0], acc[t][1], acc[t][2], acc[t][3]};
            f4 v1 = {acc[t][4], acc[t][5], acc[t][6], acc[t][7]};
            *(f4*)(pq + (tg * 8 + t) * E + eg * 8) = v0;
            *(f4*)(pq + (tg * 8 + t) * E + eg * 8 + 4) = v1;
        }
    }
}

// ---------------- kernel 2: eighth-reduce + bias + top2 + scatter ----------------
__global__ __launch_bounds__(256)
void gating_topk(const float* __restrict__ partial, const float* __restrict__ Bv,
                 float* __restrict__ out, int ntok)
{
    __shared__ float logits[64][65];
    __shared__ float sw1[64], sw2[64];
    __shared__ int   si1[64], si2[64];

    const int tid  = threadIdx.x;
    const int tok0 = blockIdx.x * 64;
    const int tok  = tid >> 2;           // 0..63
    const int seg  = tid & 3;            // 16-float expert segment
    {
        float4 s[4];
        const float* p0 = partial + ((size_t)tok0 + tok) * E + seg * 16;
#pragma unroll
        for (int c = 0; c < 4; ++c) s[c] = *(const f4*)(p0 + 4 * c);
#pragma unroll
        for (int q = 1; q < NQ; ++q) {
            const float* p = partial + ((size_t)q * ntok + tok0 + tok) * E + seg * 16;
#pragma unroll
            for (int c = 0; c < 4; ++c) {
                f4 v = *(const f4*)(p + 4 * c);
                s[c].x += v.x; s[c].y += v.y; s[c].z += v.z; s[c].w += v.w;
            }
        }
#pragma unroll
        for (int c = 0; c < 4; ++c) {
            f4 bv = *(const f4*)(Bv + seg * 16 + 4 * c);
            logits[tok][seg * 16 + 4*c + 0] = s[c].x + bv.x;
            logits[tok][seg * 16 + 4*c + 1] = s[c].y + bv.y;
            logits[tok][seg * 16 + 4*c + 2] = s[c].z + bv.z;
            logits[tok][seg * 16 + 4*c + 3] = s[c].w + bv.w;
        }
    }
    __syncthreads();

    if (tid < 64) {
        // lane = token: top-2 scan. Strict '>' matches top_k tie-breaking.
        float m1 = -3.4e38f, m2 = -3.4e38f;
        int i1 = 0, i2 = 0;
#pragma unroll
        for (int e = 0; e < E; ++e) {
            float v = logits[tid][e];
            if (v > m1)      { m2 = m1; i2 = i1; m1 = v; i1 = e; }
            else if (v > m2) { m2 = v; i2 = e; }
        }
        float p = 1.0f / (1.0f + expf(m2 - m1));   // stable: m2 <= m1
        sw1[tid] = p; sw2[tid] = 1.0f - p;
        si1[tid] = i1; si2[tid] = i2;
    }
    __syncthreads();

    float4* o4 = (float4*)(out + (size_t)tok0 * E);
#pragma unroll
    for (int p5 = 0; p5 < 4; ++p5) {
        int idx = tid + p5 * 256;        // 0..1023 float4s of the 64x64 tile
        int tl  = idx >> 4;
        int e0  = (idx & 15) * 4;
        int a1 = si1[tl], a2 = si2[tl];
        float v1 = sw1[tl], v2 = sw2[tl];
        float4 v;
        v.x = (e0 + 0 == a1) ? v1 : (e0 + 0 == a2) ? v2 : 0.0f;
        v.y = (e0 + 1 == a1) ? v1 : (e0 + 1 == a2) ? v2 : 0.0f;
        v.z = (e0 + 2 == a1) ? v1 : (e0 + 2 == a2) ? v2 : 0.0f;
        v.w = (e0 + 3 == a1) ? v1 : (e0 + 3 == a2) ? v2 : 0.0f;
        o4[idx] = v;
    }
}

// ---------------- fallback: round-7 verified single-kernel path ----------------
#define FKCH 512
#define FSK 16
#define FNSTEP (FKCH / FSK)    // 32

__device__ __forceinline__ void fb_tile_store(float* b, const float (&acc)[8][8],
                                              int tg, int eg) {
#pragma unroll
    for (int t = 0; t < 8; ++t) {
        f4 v0 = {acc[t][0], acc[t][1], acc[t][2], acc[t][3]};
        f4 v1 = {acc[t][4], acc[t][5], acc[t][6], acc[t][7]};
        *(f4*)(b + (tg * 8 + t) * 65 + eg * 8) = v0;
        *(f4*)(b + (tg * 8 + t) * 65 + eg * 8 + 4) = v1;
    }
}

__device__ __forceinline__ void fb_tile_addin(const float* b, float (&acc)[8][8],
                                              int tg, int eg) {
#pragma unroll
    for (int t = 0; t < 8; ++t) {
        f4 v0 = *(const f4*)(b + (tg * 8 + t) * 65 + eg * 8);
        f4 v1 = *(const f4*)(b + (tg * 8 + t) * 65 + eg * 8 + 4);
        acc[t][0] += v0.x; acc[t][1] += v0.y; acc[t][2] += v0.z; acc[t][3] += v0.w;
        acc[t][4] += v1.x; acc[t][5] += v1.y; acc[t][6] += v1.z; acc[t][7] += v1.w;
    }
}

__global__ __launch_bounds__(256)
void gating_fb(const float* __restrict__ x, const float* __restrict__ W,
               const float* __restrict__ Bv, float* __restrict__ out)
{
    __shared__ __align__(16) float smem[16384];

    const int tid  = threadIdx.x;
    const int lane = tid & 63;
    const int w    = __builtin_amdgcn_readfirstlane(tid >> 6);
    const int tg   = lane >> 3;
    const int eg   = lane & 7;
    const int tok0 = blockIdx.x * TOK;

    float* base  = smem + w * 4096;
    float* xbuf0 = base;
    float* xbuf1 = base + 1024;
    float* wbuf0 = base + 2048;
    float* wbuf1 = base + 3072;

    const float* xg = x + (size_t)(tok0 + lane) * D + w * FKCH;
    const float* wg = W + (size_t)w * FKCH * E;

    float acc[8][8];
#pragma unroll
    for (int t = 0; t < 8; ++t)
#pragma unroll
        for (int e = 0; e < 8; ++e) acc[t][e] = 0.f;

    float4 xs[4];
    float  ws[16];
#pragma unroll
    for (int c = 0; c < 4; ++c) xs[c] = *(const f4*)(xg + c * 4);
#pragma unroll
    for (int j = 0; j < 16; ++j) ws[j] = wg[j * E + lane];
#pragma unroll
    for (int j = 0; j < 16; ++j) xbuf0[j * 64 + lane] = fget(xs[j >> 2], j & 3);
#pragma unroll
    for (int j = 0; j < 16; ++j) wbuf0[j * 64 + lane] = ws[j];
#pragma unroll
    for (int c = 0; c < 4; ++c) xs[c] = *(const f4*)(xg + FSK + c * 4);
#pragma unroll
    for (int j = 0; j < 16; ++j) ws[j] = wg[(FSK + j) * E + lane];

    float4 xw[2][2], ww[2][2];
    xw[0][0] = *(const f4*)(xbuf0 + tg * 8);
    xw[0][1] = *(const f4*)(xbuf0 + tg * 8 + 4);
    ww[0][0] = *(const f4*)(wbuf0 + eg * 8);
    ww[0][1] = *(const f4*)(wbuf0 + eg * 8 + 4);
    xw[1][0] = *(const f4*)(xbuf0 + 64 + tg * 8);
    xw[1][1] = *(const f4*)(xbuf0 + 64 + tg * 8 + 4);
    ww[1][0] = *(const f4*)(wbuf0 + 64 + eg * 8);
    ww[1][1] = *(const f4*)(wbuf0 + 64 + eg * 8 + 4);

#pragma unroll 1
    for (int s = 0; s < FNSTEP; ++s) {
        float* xc = (s & 1) ? xbuf1 : xbuf0;
        float* wc = (s & 1) ? wbuf1 : wbuf0;
        float* xn = (s & 1) ? xbuf0 : xbuf1;
        float* wn = (s & 1) ? wbuf0 : wbuf1;
        if (s < FNSTEP - 1) {
#pragma unroll
            for (int j = 0; j < 16; ++j) xn[j * 64 + lane] = fget(xs[j >> 2], j & 3);
#pragma unroll
            for (int j = 0; j < 16; ++j) wn[j * 64 + lane] = ws[j];
            const int s2 = (s + 2 < FNSTEP) ? s + 2 : FNSTEP - 1;
#pragma unroll
            for (int c = 0; c < 4; ++c) xs[c] = *(const f4*)(xg + s2 * FSK + c * 4);
#pragma unroll
            for (int j = 0; j < 16; ++j) ws[j] = wg[(s2 * FSK + j) * E + lane];
        }
        const float* xnx = (s < FNSTEP - 1) ? xn : xc;
        const float* wnx = (s < FNSTEP - 1) ? wn : wc;
#pragma unroll
        for (int r = 0; r < FSK; ++r) {
            const int p = r & 1;
            fmablock(acc, xw[p], ww[p]);
            const float* xsrc = (r < FSK - 2) ? (xc + (r + 2) * 64)
                                              : (xnx + (r - (FSK - 2)) * 64);
            const float* wsrc = (r < FSK - 2) ? (wc + (r + 2) * 64)
                                              : (wnx + (r - (FSK - 2)) * 64);
            xw[p][0] = *(const f4*)(xsrc + tg * 8);
            xw[p][1] = *(const f4*)(xsrc + tg * 8 + 4);
            ww[p][0] = *(const f4*)(wsrc + eg * 8);
            ww[p][1] = *(const f4*)(wsrc + eg * 8 + 4);
        }
    }

    float* buf0 = smem;
    float* buf1 = smem + 4160;
    __syncthreads();
    if (w == 2) fb_tile_store(buf0, acc, tg, eg);
    if (w == 3) fb_tile_store(buf1, acc, tg, eg);
    __syncthreads();
    if (w == 0) fb_tile_addin(buf0, acc, tg, eg);
    if (w == 1) fb_tile_addin(buf1, acc, tg, eg);
    __syncthreads();
    if (w == 1) fb_tile_store(buf0, acc, tg, eg);
    __syncthreads();
    if (w == 0) {
        fb_tile_addin(buf0, acc, tg, eg);
        fb_tile_store(buf0, acc, tg, eg);
    }
    __syncthreads();

    float* logits = buf0;
    float* sw1 = smem + 8320; float* sw2 = smem + 8384;
    int*   si1 = (int*)(smem + 8448); int* si2 = (int*)(smem + 8512);

    if (w == 0) {
        float m1 = -3.4e38f, m2 = -3.4e38f;
        int i1 = 0, i2 = 0;
#pragma unroll
        for (int e = 0; e < E; ++e) {
            float v = logits[lane * 65 + e] + Bv[e];
            if (v > m1)      { m2 = m1; i2 = i1; m1 = v; i1 = e; }
            else if (v > m2) { m2 = v; i2 = e; }
        }
        float p = 1.0f / (1.0f + expf(m2 - m1));
        sw1[lane] = p; sw2[lane] = 1.0f - p;
        si1[lane] = i1; si2[lane] = i2;
    }
    __syncthreads();

    float4* o4 = (float4*)(out + (size_t)tok0 * E);
#pragma unroll
    for (int p5 = 0; p5 < 4; ++p5) {
        int idx = tid + p5 * 256;
        int tl  = idx >> 4;
        int e0  = (idx & 15) * 4;
        int a1 = si1[tl], a2 = si2[tl];
        float v1 = sw1[tl], v2 = sw2[tl];
        float4 v;
        v.x = (e0 + 0 == a1) ? v1 : (e0 + 0 == a2) ? v2 : 0.0f;
        v.y = (e0 + 1 == a1) ? v1 : (e0 + 1 == a2) ? v2 : 0.0f;
        v.z = (e0 + 2 == a1) ? v1 : (e0 + 2 == a2) ? v2 : 0.0f;
        v.w = (e0 + 3 == a1) ? v1 : (e0 + 3 == a2) ? v2 : 0.0f;
        o4[idx] = v;
    }
}

extern "C" void kernel_launch(void* const* d_in, const int* in_sizes, int n_in,
                              void* d_out, int out_size, void* d_ws, size_t ws_size,
                              hipStream_t stream) {
    const float* x = (const float*)d_in[0];
    const float* W = (const float*)d_in[1];
    const float* b = (const float*)d_in[2];
    float* out = (float*)d_out;

    const int tokens = in_sizes[0] / D;                          // 16384
    const size_t need = (size_t)NQ * tokens * E * sizeof(float); // 32 MB

    if (d_ws != nullptr && ws_size >= need && (tokens % TOK) == 0) {
        gating_mm<<<(tokens / TOK) * NQ, 128, 0, stream>>>(x, W, (float*)d_ws, tokens);
        gating_topk<<<tokens / TOK, 256, 0, stream>>>((const float*)d_ws, b, out, tokens);
    } else {
        gating_fb<<<tokens / TOK, 256, 0, stream>>>(x, W, b, out);
    }
}